// Round 1
// baseline (297.633 us; speedup 1.0000x reference)
//
#include <hip/hip_runtime.h>

// ---------------------------------------------------------------------------
// MoE cross-attention decoder layer on MI355X (gfx950), bf16 MFMA pipeline.
// Stages: convert->bf16, QKV GEMMs (MFMA 16x16x32), V transpose, flash attn,
// out-proj GEMM, gate+residual+LayerNorm finalize.
// ---------------------------------------------------------------------------

typedef __bf16 bf16x8 __attribute__((ext_vector_type(8)));
typedef float f32x4 __attribute__((ext_vector_type(4)));
typedef unsigned int u32x4 __attribute__((ext_vector_type(4)));

__device__ __forceinline__ unsigned short f2bf(float f) {
    unsigned u = __builtin_bit_cast(unsigned, f);
    u += 0x7FFFu + ((u >> 16) & 1u);
    return (unsigned short)(u >> 16);
}

__device__ __forceinline__ bf16x8 ld_bf8(const unsigned short* p) {
    return __builtin_bit_cast(bf16x8, *reinterpret_cast<const u32x4*>(p));
}

// ---------------- elementwise converts ----------------
__global__ void cvt2(const float* __restrict__ a, const float* __restrict__ b,
                     unsigned short* __restrict__ o, int n) {
    int i = blockIdx.x * 256 + threadIdx.x;
    if (i < n) o[i] = f2bf(a[i] + b[i]);
}

__global__ void cvt1(const float* __restrict__ a, unsigned short* __restrict__ o, int n) {
    int i = blockIdx.x * 256 + threadIdx.x;
    if (i < n) o[i] = f2bf(a[i]);
}

// ---------------- generic GEMM: C[M,256] = A[M,256] * W[256,256]^T ----------
// A row-major k-contiguous; W row-major [n][k] (i.e. B^T), k-contiguous.
// out = (acc + bias[col]) * scale.  64x64 tile, BK=64, 4 waves -> 32x32 each.
template <bool BF16OUT>
__launch_bounds__(256)
__global__ void gemm_bt(const unsigned short* __restrict__ A, long sAe,
                        const unsigned short* __restrict__ W, long sWe,
                        const float* __restrict__ bias, long sBe,
                        void* __restrict__ Cout, long sCe,
                        float scale)
{
    const int e = blockIdx.z;
    A += (size_t)e * sAe;
    W += (size_t)e * sWe;
    bias += (size_t)e * sBe;
    const int row0 = blockIdx.x * 64;
    const int col0 = blockIdx.y * 64;
    __shared__ unsigned short As[64 * 72];  // stride 72 el (144B): 16B-aligned rows, 2-way-max banks
    __shared__ unsigned short Bs[64 * 72];
    const int tid  = threadIdx.x;
    const int lane = tid & 63;
    const int l15  = lane & 15;
    const int quad = lane >> 4;
    const int wid  = tid >> 6;
    const int wm   = (wid >> 1) * 32;
    const int wn   = (wid & 1) * 32;
    const int lr   = tid >> 2;        // staging row 0..63
    const int ls   = (tid & 3) * 16;  // staging k-seg 0,16,32,48

    f32x4 acc[2][2] = {};

    for (int k0 = 0; k0 < 256; k0 += 64) {
        const u32x4* ga = reinterpret_cast<const u32x4*>(A + (size_t)(row0 + lr) * 256 + k0 + ls);
        const u32x4* gb = reinterpret_cast<const u32x4*>(W + (size_t)(col0 + lr) * 256 + k0 + ls);
        u32x4 a0 = ga[0], a1 = ga[1];
        u32x4 b0 = gb[0], b1 = gb[1];
        *reinterpret_cast<u32x4*>(&As[lr * 72 + ls])     = a0;
        *reinterpret_cast<u32x4*>(&As[lr * 72 + ls + 8]) = a1;
        *reinterpret_cast<u32x4*>(&Bs[lr * 72 + ls])     = b0;
        *reinterpret_cast<u32x4*>(&Bs[lr * 72 + ls + 8]) = b1;
        __syncthreads();
#pragma unroll
        for (int kk = 0; kk < 64; kk += 32) {
            bf16x8 af0 = ld_bf8(&As[(wm + l15) * 72 + kk + quad * 8]);
            bf16x8 af1 = ld_bf8(&As[(wm + 16 + l15) * 72 + kk + quad * 8]);
            bf16x8 bf0 = ld_bf8(&Bs[(wn + l15) * 72 + kk + quad * 8]);
            bf16x8 bf1 = ld_bf8(&Bs[(wn + 16 + l15) * 72 + kk + quad * 8]);
            acc[0][0] = __builtin_amdgcn_mfma_f32_16x16x32_bf16(af0, bf0, acc[0][0], 0, 0, 0);
            acc[0][1] = __builtin_amdgcn_mfma_f32_16x16x32_bf16(af0, bf1, acc[0][1], 0, 0, 0);
            acc[1][0] = __builtin_amdgcn_mfma_f32_16x16x32_bf16(af1, bf0, acc[1][0], 0, 0, 0);
            acc[1][1] = __builtin_amdgcn_mfma_f32_16x16x32_bf16(af1, bf1, acc[1][1], 0, 0, 0);
        }
        __syncthreads();
    }
#pragma unroll
    for (int mi = 0; mi < 2; ++mi) {
#pragma unroll
        for (int ni = 0; ni < 2; ++ni) {
            const int col = col0 + wn + ni * 16 + l15;
            const float bv = bias[col];
#pragma unroll
            for (int r = 0; r < 4; ++r) {
                const int row = row0 + wm + mi * 16 + quad * 4 + r;
                float v = (acc[mi][ni][r] + bv) * scale;
                if constexpr (BF16OUT)
                    reinterpret_cast<unsigned short*>(Cout)[(size_t)e * sCe + (size_t)row * 256 + col] = f2bf(v);
                else
                    reinterpret_cast<float*>(Cout)[(size_t)e * sCe + (size_t)row * 256 + col] = v;
            }
        }
    }
}

// ---------------- V transpose: Vb[e][lk][b][d] -> VT[e][b][d][lk] ----------
__launch_bounds__(256)
__global__ void transpose_v(const unsigned short* __restrict__ Vb,
                            unsigned short* __restrict__ VT)
{
    const int e  = blockIdx.x >> 8;
    const int b  = (blockIdx.x >> 4) & 15;
    const int kc = blockIdx.x & 15;
    const int k0 = kc * 64;
    __shared__ unsigned short T[64 * 266];  // stride 266: phase-2 column reads 2-way max
    const int tid = threadIdx.x;
    // read phase: thread -> (kpos row r = tid&63, dim seg = (tid>>6)*64)
    {
        const int r   = tid & 63;
        const int seg = (tid >> 6) * 64;
        const u32x4* src = reinterpret_cast<const u32x4*>(
            Vb + ((size_t)(e * 1024 + k0 + r) * 16 + b) * 256 + seg);
        unsigned* T32 = reinterpret_cast<unsigned*>(T);
#pragma unroll
        for (int u = 0; u < 8; ++u) {
            u32x4 v = src[u];
            int base = (r * 266 + seg + u * 8) >> 1;
            T32[base + 0] = v[0];
            T32[base + 1] = v[1];
            T32[base + 2] = v[2];
            T32[base + 3] = v[3];
        }
    }
    __syncthreads();
    // write phase: wave w covers dims w*64..w*64+63; lane l -> kpos k0+l
    {
        const int w = tid >> 6;
        const int l = tid & 63;
        const size_t obase = ((size_t)(e * 16 + b) * 256) * 1024 + k0 + l;
#pragma unroll 8
        for (int di = 0; di < 64; ++di) {
            int dim = w * 64 + di;
            VT[obase + (size_t)dim * 1024] = T[l * 266 + dim];
        }
    }
}

// ---------------- flash attention, 1 wave per (qtile16, h, e, b) -----------
__launch_bounds__(64)
__global__ void attn(const unsigned short* __restrict__ Qb,
                     const unsigned short* __restrict__ Kb,
                     const unsigned short* __restrict__ VT,
                     unsigned short* __restrict__ CTX)
{
    const int qt = blockIdx.x;   // 0..6  (16 q-rows each; rows >=100 padded)
    const int h  = blockIdx.y;   // 0..7
    const int z  = blockIdx.z;   // 0..79
    const int e = z >> 4, b = z & 15;
    const int lane = threadIdx.x;
    const int l15 = lane & 15, quad = lane >> 4;
    __shared__ unsigned short Ps[16 * 40];  // P tile C->A layout round-trip

    // Q fragment: A[m=l15][k=quad*8+j], q pre-scaled by 1/sqrt(hd) in GEMM
    u32x4 qraw = {0u, 0u, 0u, 0u};
    {
        const int l = qt * 16 + l15;
        if (l < 100)
            qraw = *reinterpret_cast<const u32x4*>(
                Qb + ((size_t)((e * 100 + l) * 16 + b)) * 256 + h * 32 + quad * 8);
    }
    const bf16x8 qf = __builtin_bit_cast(bf16x8, qraw);

    f32x4 o0 = {}, o1 = {};
    float mrow[4], lrow[4];
#pragma unroll
    for (int r = 0; r < 4; ++r) { mrow[r] = -1e30f; lrow[r] = 0.0f; }

    const unsigned short* kbase = Kb + ((size_t)e * 1024 * 16 + b) * 256 + h * 32;
    const unsigned short* vbase = VT + (((size_t)(e * 16 + b) * 256) + h * 32) * 1024;
    const f32x4 zacc = {};

    for (int kt = 0; kt < 32; ++kt) {
        const unsigned short* kp = kbase + (size_t)kt * 32 * 4096;
        bf16x8 kf0 = ld_bf8(kp + (size_t)l15 * 4096 + quad * 8);
        bf16x8 kf1 = ld_bf8(kp + (size_t)(16 + l15) * 4096 + quad * 8);
        f32x4 s0 = __builtin_amdgcn_mfma_f32_16x16x32_bf16(qf, kf0, zacc, 0, 0, 0);
        f32x4 s1 = __builtin_amdgcn_mfma_f32_16x16x32_bf16(qf, kf1, zacc, 0, 0, 0);

#pragma unroll
        for (int r = 0; r < 4; ++r) {
            float mx = fmaxf(s0[r], s1[r]);
            mx = fmaxf(mx, __shfl_xor(mx, 1, 16));
            mx = fmaxf(mx, __shfl_xor(mx, 2, 16));
            mx = fmaxf(mx, __shfl_xor(mx, 4, 16));
            mx = fmaxf(mx, __shfl_xor(mx, 8, 16));
            const float mnew  = fmaxf(mrow[r], mx);
            const float alpha = __expf(mrow[r] - mnew);
            const float p0 = __expf(s0[r] - mnew);
            const float p1 = __expf(s1[r] - mnew);
            float ps = p0 + p1;
            ps += __shfl_xor(ps, 1, 16);
            ps += __shfl_xor(ps, 2, 16);
            ps += __shfl_xor(ps, 4, 16);
            ps += __shfl_xor(ps, 8, 16);
            lrow[r] = lrow[r] * alpha + ps;
            mrow[r] = mnew;
            o0[r] *= alpha;
            o1[r] *= alpha;
            Ps[(quad * 4 + r) * 40 + l15]      = f2bf(p0);
            Ps[(quad * 4 + r) * 40 + 16 + l15] = f2bf(p1);
        }
        __syncthreads();  // single wave: orders LDS write->read
        bf16x8 pf  = ld_bf8(&Ps[l15 * 40 + quad * 8]);
        bf16x8 vf0 = ld_bf8(vbase + (size_t)l15 * 1024 + kt * 32 + quad * 8);
        bf16x8 vf1 = ld_bf8(vbase + (size_t)(16 + l15) * 1024 + kt * 32 + quad * 8);
        o0 = __builtin_amdgcn_mfma_f32_16x16x32_bf16(pf, vf0, o0, 0, 0, 0);
        o1 = __builtin_amdgcn_mfma_f32_16x16x32_bf16(pf, vf1, o1, 0, 0, 0);
        __syncthreads();
    }

#pragma unroll
    for (int r = 0; r < 4; ++r) {
        const int row = qt * 16 + quad * 4 + r;
        if (row < 100) {
            const float inv = 1.0f / lrow[r];
            const size_t o = ((size_t)((e * 100 + row) * 16 + b)) * 256 + h * 32;
            CTX[o + l15]      = f2bf(o0[r] * inv);
            CTX[o + 16 + l15] = f2bf(o1[r] * inv);
        }
    }
}

// ---------------- gate + mix + residual + LayerNorm ------------------------
__launch_bounds__(256)
__global__ void finalize(const float* __restrict__ tgt, const float* __restrict__ w_gate,
                         const float* __restrict__ b_gate, const float* __restrict__ OUTf,
                         const float* __restrict__ gamma, const float* __restrict__ beta,
                         float* __restrict__ out)
{
    const int row = blockIdx.x;      // (l,b) flat, 0..1599
    const int d = threadIdx.x;       // 0..255
    __shared__ float red[4];
    const float t = tgt[(size_t)row * 256 + d];

    float g[5];
#pragma unroll
    for (int e = 0; e < 5; ++e) {
        float part = t * w_gate[e * 256 + d];
#pragma unroll
        for (int off = 32; off >= 1; off >>= 1) part += __shfl_xor(part, off, 64);
        if ((d & 63) == 0) red[d >> 6] = part;
        __syncthreads();
        g[e] = red[0] + red[1] + red[2] + red[3] + b_gate[e];
        __syncthreads();
    }
    float mx = g[0];
#pragma unroll
    for (int e = 1; e < 5; ++e) mx = fmaxf(mx, g[e]);
    float s = 0.0f;
#pragma unroll
    for (int e = 0; e < 5; ++e) { g[e] = __expf(g[e] - mx); s += g[e]; }
    const float invs = 1.0f / s;

    float mo = 0.0f;
#pragma unroll
    for (int e = 0; e < 5; ++e)
        mo += g[e] * invs * OUTf[((size_t)e * 1600 + row) * 256 + d];
    const float x = t + mo;

    float part = x;
#pragma unroll
    for (int off = 32; off >= 1; off >>= 1) part += __shfl_xor(part, off, 64);
    if ((d & 63) == 0) red[d >> 6] = part;
    __syncthreads();
    const float mean = (red[0] + red[1] + red[2] + red[3]) * (1.0f / 256.0f);
    __syncthreads();

    const float diff = x - mean;
    part = diff * diff;
#pragma unroll
    for (int off = 32; off >= 1; off >>= 1) part += __shfl_xor(part, off, 64);
    if ((d & 63) == 0) red[d >> 6] = part;
    __syncthreads();
    const float var = (red[0] + red[1] + red[2] + red[3]) * (1.0f / 256.0f);

    out[(size_t)row * 256 + d] = diff * rsqrtf(var + 1e-5f) * gamma[d] + beta[d];
}

// ---------------------------------------------------------------------------
extern "C" void kernel_launch(void* const* d_in, const int* in_sizes, int n_in,
                              void* d_out, int out_size, void* d_ws, size_t ws_size,
                              hipStream_t stream)
{
    const float* tgt    = (const float*)d_in[0];
    const float* mem    = (const float*)d_in[1];
    const float* qpos   = (const float*)d_in[2];
    const float* pos    = (const float*)d_in[3];
    const float* w_in   = (const float*)d_in[4];
    const float* b_in   = (const float*)d_in[5];
    const float* w_out  = (const float*)d_in[6];
    const float* b_out  = (const float*)d_in[7];
    const float* w_gate = (const float*)d_in[8];
    const float* b_gate = (const float*)d_in[9];
    const float* ln_g   = (const float*)d_in[10];
    const float* ln_b   = (const float*)d_in[11];
    float* out = (float*)d_out;

    char* p = (char*)d_ws;
    auto alloc = [&](size_t n) { char* r = p; p += (n + 255) & ~(size_t)255; return r; };

    unsigned short* Aq  = (unsigned short*)alloc(409600ull * 2);        // bf16(tgt+query_pos)
    unsigned short* Ak  = (unsigned short*)alloc(4194304ull * 2);       // bf16(memory+pos)
    unsigned short* Av  = (unsigned short*)alloc(4194304ull * 2);       // bf16(memory)
    unsigned short* Wb  = (unsigned short*)alloc(983040ull * 2);        // bf16 w_in
    unsigned short* WOb = (unsigned short*)alloc(327680ull * 2);        // bf16 w_out
    unsigned short* Qb  = (unsigned short*)alloc(5ull * 409600 * 2);    // q  [e][l][b][d]
    unsigned short* Kb  = (unsigned short*)alloc(5ull * 4194304 * 2);   // k  [e][lk][b][d]
    unsigned short* Vb  = (unsigned short*)alloc(5ull * 4194304 * 2);   // v  [e][lk][b][d]
    unsigned short* VTb = (unsigned short*)alloc(5ull * 4194304 * 2);   // v^T[e][b][d][lk]
    // Vb region is dead after transpose_v: reuse it for ctx (bf16) and out (f32)
    unsigned short* CTXb = Vb;                                          // 4,096,000 B
    float* OUTf = (float*)((char*)Vb + 8388608);                        // 8,192,000 B

    cvt2<<<1600, 256, 0, stream>>>(tgt, qpos, Aq, 409600);
    cvt2<<<16384, 256, 0, stream>>>(mem, pos, Ak, 4194304);
    cvt1<<<16384, 256, 0, stream>>>(mem, Av, 4194304);
    cvt1<<<3840, 256, 0, stream>>>(w_in, Wb, 983040);
    cvt1<<<1280, 256, 0, stream>>>(w_out, WOb, 327680);

    const float qscale = 0.17677669529663687f;  // 1/sqrt(32), applied after bias like ref
    // Q: M=1600
    gemm_bt<true><<<dim3(25, 4, 5), 256, 0, stream>>>(
        Aq, 0, Wb, 196608, b_in, 768, Qb, 409600, qscale);
    // K: M=16384
    gemm_bt<true><<<dim3(256, 4, 5), 256, 0, stream>>>(
        Ak, 0, Wb + 65536, 196608, b_in + 256, 768, Kb, 4194304, 1.0f);
    // V: M=16384
    gemm_bt<true><<<dim3(256, 4, 5), 256, 0, stream>>>(
        Av, 0, Wb + 131072, 196608, b_in + 512, 768, Vb, 4194304, 1.0f);

    transpose_v<<<1280, 256, 0, stream>>>(Vb, VTb);

    attn<<<dim3(7, 8, 80), 64, 0, stream>>>(Qb, Kb, VTb, CTXb);

    // out-proj: M=1600, fp32 out
    gemm_bt<false><<<dim3(25, 4, 5), 256, 0, stream>>>(
        CTXb, 409600, WOb, 65536, b_out, 256, OUTf, 409600, 1.0f);

    finalize<<<1600, 256, 0, stream>>>(tgt, w_gate, b_gate, OUTf, ln_g, ln_b, out);
}